// Round 9
// baseline (224.399 us; speedup 1.0000x reference)
//
#include <hip/hip_runtime.h>
#include <hip/hip_bf16.h>

#define N_NODES 50000
#define N_EDGES 800000
#define C 128
#define D_IN 32
#define T0 25000
#define OUT_DIM 16
#define CAPN 64                               // per-node slot capacity
#define ENC_BLOCKS 512
#define NSCAT 1024
#define PREP_ITEMS (2 * 128 * 256 + 2 * 16 * 128 + N_NODES)
#define PREP_BLOCKS ((PREP_ITEMS + 255) / 256)

// Pipeline (6 dispatches): mega{enc+prep+cnt-zero} -> scatter -> [agg->gemm]x2.
// NO CSR build: src_sorted has FIXED per-node regions of CAPN=64 slots
// (deg ~ Poisson(16); P(deg>=64) ~ 1e-10/node). scatter does
// c=atomicAdd(&cnt[dst]); src_sorted[dst*64+c]=src in one pass.
// Aggregate derives beg=node*64 arithmetically (no nodeinfo load) and
// inv=1/max(cnt,1) (no inv_deg load).
// Feature storage: bf16 plane xh[N][128] (GEMM self operand) + fp8 e4m3
// plane xf8[N][128] (gather operand ONLY; one 128-B line per row).
// GEMM K=256: segs {xh*Ws_hi, ah*Wn_hi}. Layer-1 fuses the head.
// Aggregate: TWO nodes per wave; 16 edge-slots/node/iter; 1 uint4 index
// load (next-iter prefetched) + 8 uint2 fp8 row gathers in flight;
// out-of-range slots use CONSTANT row 0 and are predicated out.

typedef __attribute__((ext_vector_type(8))) short short8;
typedef __attribute__((ext_vector_type(4))) float f32x4;
typedef __attribute__((ext_vector_type(2))) float f32x2;

__device__ __forceinline__ unsigned short f2bf(float f) {
    union { float f; unsigned int i; } u; u.f = f;
    unsigned int x = u.i;
    unsigned int r = x + 0x7fffu + ((x >> 16) & 1u);
    return (unsigned short)(r >> 16);
}
__device__ __forceinline__ float bf2f(unsigned short h) {
    union { unsigned int i; float f; } u; u.i = ((unsigned int)h) << 16;
    return u.f;
}
__device__ __forceinline__ float lo_f(unsigned int w) {
    union { unsigned int i; float f; } u; u.i = w << 16;
    return u.f;
}
__device__ __forceinline__ float hi_f(unsigned int w) {
    union { unsigned int i; float f; } u; u.i = w & 0xffff0000u;
    return u.f;
}
__device__ __forceinline__ void async16(void* lds, const void* g) {
    __builtin_amdgcn_global_load_lds(
        (const __attribute__((address_space(1))) void*)g,
        (__attribute__((address_space(3))) void*)lds, 16, 0, 0);
}
// decode 8 fp8 (e4m3) bytes -> accumulate into a[0..7]
__device__ __forceinline__ void add8f8(float* a, uint2 v) {
    f32x2 p;
    p = __builtin_amdgcn_cvt_pk_f32_fp8(v.x, false); a[0] += p.x; a[1] += p.y;
    p = __builtin_amdgcn_cvt_pk_f32_fp8(v.x, true);  a[2] += p.x; a[3] += p.y;
    p = __builtin_amdgcn_cvt_pk_f32_fp8(v.y, false); a[4] += p.x; a[5] += p.y;
    p = __builtin_amdgcn_cvt_pk_f32_fp8(v.y, true);  a[6] += p.x; a[7] += p.y;
}
// pack 8 floats -> 8 fp8 (e4m3) bytes, RNE+saturate
__device__ __forceinline__ uint2 pack8f8(const float* a) {
    int w0 = 0, w1 = 0;
    w0 = __builtin_amdgcn_cvt_pk_fp8_f32(a[0], a[1], w0, false);
    w0 = __builtin_amdgcn_cvt_pk_fp8_f32(a[2], a[3], w0, true);
    w1 = __builtin_amdgcn_cvt_pk_fp8_f32(a[4], a[5], w1, false);
    w1 = __builtin_amdgcn_cvt_pk_fp8_f32(a[6], a[7], w1, true);
    return make_uint2((unsigned)w0, (unsigned)w1);
}

// ---------------------------------------------------------------------------
// Mega-kernel: encode (blocks 0..511, row_idx software-pipelined) +
// weight prep + cnt-zero (blocks 512..).
// ---------------------------------------------------------------------------
__global__ __launch_bounds__(256) void encode_prep_kernel(
    const float* __restrict__ feats0, const float* __restrict__ feats1,
    const float* __restrict__ w0, const float* __restrict__ b0,
    const float* __restrict__ w1, const float* __restrict__ b1,
    const int* __restrict__ row_idx, unsigned short* __restrict__ xh,
    unsigned char* __restrict__ xf8,
    int* __restrict__ cnt,
    const float* __restrict__ ws0, const float* __restrict__ wn0,
    const float* __restrict__ ws1, const float* __restrict__ wn1,
    const float* __restrict__ hw,
    unsigned short* __restrict__ BT0, unsigned short* __restrict__ BT1,
    unsigned short* __restrict__ hwbh, unsigned short* __restrict__ hwbl)
{
    if (blockIdx.x >= ENC_BLOCKS) {
        // ---- weight prep + cnt zero ----
        int idx = (blockIdx.x - ENC_BLOCKS) * 256 + threadIdx.x;
        const int per_layer = 128 * 256;
        if (idx < 2 * per_layer) {
            int lyr = idx / per_layer;
            int rem = idx - lyr * per_layer;
            int n = rem >> 8;
            int k = rem & 255;
            int seg = k >> 7;     // 0:Ws_hi 1:Wn_hi
            int ch = k & 127;
            const float* W = (lyr == 0) ? (seg ? wn0 : ws0)
                                        : (seg ? wn1 : ws1);
            (lyr == 0 ? BT0 : BT1)[(size_t)n * 256 + k] =
                f2bf(W[ch * 128 + n]);
            return;
        }
        int jdx = idx - 2 * per_layer;
        if (jdx < 2 * 16 * 128) {
            int plane = jdx >> 11;
            int rem = jdx & 2047;
            int n = rem >> 7;
            int k = rem & 127;
            float v = hw[k * OUT_DIM + n];
            unsigned short hi = f2bf(v);
            (plane ? hwbl : hwbh)[n * 136 + k] = plane ? f2bf(v - bf2f(hi)) : hi;
            return;
        }
        int zdx = jdx - 2 * 16 * 128;
        if (zdx < N_NODES) cnt[zdx] = 0;
        return;
    }

    // ---- encode (pipelined row_idx prefetch) ----
    __shared__ float sw0[D_IN * C];
    __shared__ float sw1[D_IN * C];
    __shared__ float sb0[C];
    __shared__ float sb1[C];
    for (int i = threadIdx.x; i < D_IN * C; i += blockDim.x) {
        sw0[i] = w0[i];
        sw1[i] = w1[i];
    }
    if (threadIdx.x < C) {
        sb0[threadIdx.x] = b0[threadIdx.x];
        sb1[threadIdx.x] = b1[threadIdx.x];
    }
    __syncthreads();

    const int STEP = ENC_BLOCKS * 16;
    int j = threadIdx.x & 15;
    int ln = threadIdx.x >> 4;
    int n = blockIdx.x * 16 + ln;
    int r = (n < N_NODES) ? row_idx[n] : 0;
    for (; n < N_NODES; n += STEP) {
        int nn = n + STEP;
        int rn = (nn < N_NODES) ? row_idx[nn] : 0;
        const float* f = (r < T0) ? (feats0 + (size_t)r * D_IN)
                                  : (feats1 + (size_t)(r - T0) * D_IN);
        const float* W = (r < T0) ? sw0 : sw1;
        const float* B = (r < T0) ? sb0 : sb1;
        float4 f4[8];
#pragma unroll
        for (int i = 0; i < 8; ++i) f4[i] = ((const float4*)f)[i];
        float acc[8];
#pragma unroll
        for (int cc = 0; cc < 8; ++cc) acc[cc] = B[8 * j + cc];
#pragma unroll
        for (int k = 0; k < D_IN; ++k) {
            float fk = ((const float*)f4)[k];
            float4 wa = *(const float4*)&W[k * C + 8 * j];
            float4 wb = *(const float4*)&W[k * C + 8 * j + 4];
            acc[0] += fk * wa.x; acc[1] += fk * wa.y;
            acc[2] += fk * wa.z; acc[3] += fk * wa.w;
            acc[4] += fk * wb.x; acc[5] += fk * wb.y;
            acc[6] += fk * wb.z; acc[7] += fk * wb.w;
        }
        short8 h8;
#pragma unroll
        for (int cc = 0; cc < 8; ++cc) h8[cc] = (short)f2bf(acc[cc]);
        *(short8*)(xh + (size_t)n * 128 + 8 * j) = h8;
        *(uint2*)(xf8 + (size_t)n * 128 + 8 * j) = pack8f8(acc);
        r = rn;
    }
}

// ---------------------------------------------------------------------------
// scatter: single-pass binning. c=atomicAdd(&cnt[dst]); ss[dst*64+c]=src.
// ---------------------------------------------------------------------------
__global__ __launch_bounds__(256) void scatter_kernel(
    const int* __restrict__ src, const int* __restrict__ dst,
    int* __restrict__ cnt, unsigned short* __restrict__ ss)
{
    int t = blockIdx.x * 256 + threadIdx.x;
    for (int e = t; e < N_EDGES; e += NSCAT * 256) {
        int d = dst[e];
        int s = src[e];
        int c = atomicAdd(&cnt[d], 1);
        ss[(size_t)d * CAPN + c] = (unsigned short)s;
    }
}

// ---------------------------------------------------------------------------
// Aggregate: TWO nodes per wave. lane = p*32 + h*16 + u; p selects node,
// h the 8-slot half of the node's 16-slot window, u the channel group.
// beg = node*CAPN (arithmetic, no load); end = beg + cnt[node].
// Gathers fp8 rows (128 B = ONE cache line each): 1 uint4 index load
// (next-iter prefetched) + 8 uint2 row gathers in flight per iteration.
// Out-of-range slots use constant row 0 and are predicated out.
// ---------------------------------------------------------------------------
__global__ __launch_bounds__(256, 8) void aggregate_kernel(
    const unsigned char* __restrict__ xf8, const int* __restrict__ cnt,
    const unsigned short* __restrict__ src_sorted,
    unsigned short* __restrict__ ah)
{
    int wpair = (blockIdx.x * blockDim.x + threadIdx.x) >> 6;
    int lane = threadIdx.x & 63;
    if (wpair >= N_NODES / 2) return;
    int p = lane >> 5;
    int h = (lane >> 4) & 1;
    int u = lane & 15;
    int node = wpair * 2 + p;
    int c = cnt[node];
    int beg = node * CAPN;
    int end = beg + c;
    float inv = 1.0f / (float)(c > 0 ? c : 1);
    const unsigned char* xu = xf8 + u * 8;
    float acc[8];
#pragma unroll
    for (int j = 0; j < 8; ++j) acc[j] = 0.f;

    if (c > 0) {
        uint4 sv = *(const uint4*)(src_sorted + beg + h * 8);
        for (int e = beg; e < end; e += 16) {
            // prefetch next window's indices (overflow lands in the next
            // node's allocated region; values unused on last iteration)
            uint4 svn = *(const uint4*)(src_sorted + e + 16 + h * 8);
            int b8 = e + h * 8;
            uint2 v[8];
#pragma unroll
            for (int t = 0; t < 8; ++t) {
                unsigned int w2 = ((const unsigned int*)&sv)[t >> 1];
                int row = (t & 1) ? (int)(w2 >> 16) : (int)(w2 & 0xffffu);
                int idx = b8 + t;
                if (idx >= end) row = 0;
                v[t] = *(const uint2*)(xu + (size_t)row * 128);
            }
#pragma unroll
            for (int t = 0; t < 8; ++t) {
                int idx = b8 + t;
                if (idx < end) add8f8(acc, v[t]);
            }
            sv = svn;
        }
    }

    // reduce across the two 8-slot halves (h dimension) within each node
#pragma unroll
    for (int j = 0; j < 8; ++j)
        acc[j] += __shfl_xor(acc[j], 16);
    if ((lane & 16) == 0) {
        short8 hv;
#pragma unroll
        for (int j = 0; j < 8; ++j)
            hv[j] = (short)f2bf(acc[j] * inv);
        *(short8*)(ah + (size_t)node * 128 + u * 8) = hv;
    }
}

// ---------------------------------------------------------------------------
// Layer GEMM: 512 thr / 8 waves, tile 128x128, K=256 in 2 chunks of 128:
// {xh*Ws_hi, ah*Wn_hi}. BT row = 256 slots (512 B).
// mode=1: relu, write xh (bf16) + xf8 (fp8) planes. mode=2: fused head.
// ---------------------------------------------------------------------------
#define BM 128
__global__ __launch_bounds__(512) void gemm_mfma(
    unsigned short* __restrict__ xh, const unsigned short* __restrict__ ah,
    unsigned char* __restrict__ xf8,
    const unsigned short* __restrict__ BT, const float* __restrict__ bias,
    int mode,
    const unsigned short* __restrict__ hwbh,
    const unsigned short* __restrict__ hwbl,
    const float* __restrict__ hb, float* __restrict__ out)
{
    __shared__ uint4 smem4[4096];           // 64 KB: As 32K | Bs 32K / th
    char* As = (char*)smem4;
    char* Bs = (char*)smem4 + 32768;
    __shared__ float bias_s[C];
    __shared__ unsigned short hwh_s[16 * 136];
    __shared__ unsigned short hwl_s[16 * 136];
    __shared__ float hb_s[OUT_DIM];

    int tid = threadIdx.x;
    int w = tid >> 6, l = tid & 63;
    int row0 = blockIdx.x * BM;
    if (tid < C) bias_s[tid] = bias[tid];
    if (mode == 2) {
        for (int i = tid; i < 16 * 136; i += 512) {
            hwh_s[i] = hwbh[i];
            hwl_s[i] = hwbl[i];
        }
        if (tid < OUT_DIM) hb_s[tid] = hb[tid];
    }

    f32x4 acc[2][4];
#pragma unroll
    for (int mt = 0; mt < 2; ++mt)
#pragma unroll
        for (int nt = 0; nt < 4; ++nt)
            acc[mt][nt] = (f32x4)(0.f);

    int wm = w & 3;
    int wn = w >> 2;
    int quad = l >> 4;
    int mrow = l & 15;

    for (int c = 0; c < 2; ++c) {
        const char* abase = (const char*)(c == 0 ? xh : ah);
#pragma unroll
        for (int i = 0; i < 4; ++i) {
            int off = i * 8192 + tid * 16;
            int rl = off >> 8;
            int row = row0 + rl;
            if (row > N_NODES - 1) row = N_NODES - 1;
            int u = ((off >> 4) & 15) ^ (rl & 15);
            async16(As + off, abase + (size_t)row * 256 + u * 16);
        }
#pragma unroll
        for (int i = 0; i < 4; ++i) {
            int off = i * 8192 + tid * 16;
            int n = off >> 8;
            int u = ((off >> 4) & 15) ^ (n & 15);
            async16(Bs + off, (const char*)BT + (size_t)n * 512 + c * 256 + u * 16);
        }
        __syncthreads();
#pragma unroll
        for (int ks = 0; ks < 4; ++ks) {
            int cu = ks * 4 + quad;
            int swz = (cu ^ mrow) * 16;
            short8 a0 = *(const short8*)(As + (wm * 32 + mrow) * 256 + swz);
            short8 a1 = *(const short8*)(As + (wm * 32 + 16 + mrow) * 256 + swz);
            short8 b[4];
#pragma unroll
            for (int nt = 0; nt < 4; ++nt)
                b[nt] = *(const short8*)(Bs + (wn * 64 + nt * 16 + mrow) * 256 + swz);
#pragma unroll
            for (int nt = 0; nt < 4; ++nt) {
                acc[0][nt] = __builtin_amdgcn_mfma_f32_16x16x32_bf16(a0, b[nt], acc[0][nt], 0, 0, 0);
                acc[1][nt] = __builtin_amdgcn_mfma_f32_16x16x32_bf16(a1, b[nt], acc[1][nt], 0, 0, 0);
            }
        }
        __syncthreads();
    }

    // epilogue: bf16 tile in LDS, XOR-swizzled (unit' = unit ^ (rl&15))
    char* th = (char*)smem4;            // 32 KB: 128 rows x 256 B
    int relu = (mode == 1);
#pragma unroll
    for (int mt = 0; mt < 2; ++mt)
#pragma unroll
        for (int nt = 0; nt < 4; ++nt) {
            int col = wn * 64 + nt * 16 + mrow;
#pragma unroll
            for (int r = 0; r < 4; ++r) {
                int rl = wm * 32 + mt * 16 + quad * 4 + r;
                float v = acc[mt][nt][r] + bias_s[col];
                if (relu) v = fmaxf(v, 0.f);
                int su = (col >> 3) ^ (rl & 15);
                *(unsigned short*)(th + rl * 256 + su * 16 + (col & 7) * 2) =
                    f2bf(v);
            }
        }
    __syncthreads();

    if (mode == 1) {
        // unswizzling copy-out to xh (bf16) + xf8 (fp8)
#pragma unroll
        for (int i = 0; i < 4; ++i) {
            int off = i * 8192 + tid * 16;
            int rl = off >> 8;
            int su = (((off >> 4) & 15) ^ (rl & 15)) * 16;
            int row = row0 + rl;
            if (row < N_NODES) {
                uint4 tv = *(const uint4*)(th + rl * 256 + su);
                *(uint4*)((char*)xh + (size_t)row * 256 + (off & 255)) = tv;
                float fv[8];
                fv[0] = lo_f(tv.x); fv[1] = hi_f(tv.x);
                fv[2] = lo_f(tv.y); fv[3] = hi_f(tv.y);
                fv[4] = lo_f(tv.z); fv[5] = hi_f(tv.z);
                fv[6] = lo_f(tv.w); fv[7] = hi_f(tv.w);
                *(uint2*)(xf8 + (size_t)row * 128 + ((off & 255) >> 1)) =
                    pack8f8(fv);
            }
        }
    } else {
        // fused head: out_tile = th @ (hwh + hwl) + hb
        f32x4 hacc = (f32x4)(0.f);
        const unsigned short* Bp[2] = {hwh_s, hwl_s};
#pragma unroll
        for (int ps = 0; ps < 2; ++ps) {
#pragma unroll
            for (int ks = 0; ks < 4; ++ks) {
                int su = ((ks * 4 + quad) ^ mrow) * 16;
                short8 a = *(const short8*)(th + (w * 16 + mrow) * 256 + su);
                short8 b = *(const short8*)((const char*)Bp[ps] +
                                            mrow * 272 + ks * 64 + quad * 16);
                hacc = __builtin_amdgcn_mfma_f32_16x16x32_bf16(a, b, hacc, 0, 0, 0);
            }
        }
        float bb = hb_s[mrow];
#pragma unroll
        for (int r = 0; r < 4; ++r) {
            int grow = row0 + w * 16 + quad * 4 + r;
            if (grow < N_NODES)
                out[(size_t)grow * OUT_DIM + mrow] = hacc[r] + bb;
        }
    }
}

// ---------------------------------------------------------------------------
extern "C" void kernel_launch(void* const* d_in, const int* in_sizes, int n_in,
                              void* d_out, int out_size, void* d_ws, size_t ws_size,
                              hipStream_t stream)
{
    const float* feats0 = (const float*)d_in[0];
    const float* feats1 = (const float*)d_in[1];
    const float* enc_w0 = (const float*)d_in[2];
    const float* enc_b0 = (const float*)d_in[3];
    const float* enc_w1 = (const float*)d_in[4];
    const float* enc_b1 = (const float*)d_in[5];
    const float* w_self0 = (const float*)d_in[6];
    const float* w_neigh0 = (const float*)d_in[7];
    const float* b0 = (const float*)d_in[8];
    const float* w_self1 = (const float*)d_in[9];
    const float* w_neigh1 = (const float*)d_in[10];
    const float* b1 = (const float*)d_in[11];
    const float* head_w = (const float*)d_in[12];
    const float* head_b = (const float*)d_in[13];
    const int* node_row_idx = (const int*)d_in[14];
    const int* edge_index = (const int*)d_in[15];
    const int* e_src = edge_index;
    const int* e_dst = edge_index + N_EDGES;

    char* p = (char*)d_ws;
    unsigned short* xh = (unsigned short*)p;  p += (size_t)N_NODES * C * 2;
    unsigned short* ah = (unsigned short*)p;  p += (size_t)N_NODES * C * 2;
    unsigned char* xf8 = (unsigned char*)p;   p += (size_t)N_NODES * C;
    unsigned short* BT0 = (unsigned short*)p; p += (size_t)128 * 256 * 2;
    unsigned short* BT1 = (unsigned short*)p; p += (size_t)128 * 256 * 2;
    unsigned short* hwbh = (unsigned short*)p; p += (size_t)16 * 136 * 2;
    unsigned short* hwbl = (unsigned short*)p; p += (size_t)16 * 136 * 2;
    int* cnt = (int*)p;            p += (size_t)(N_NODES + 8) * 4;
    unsigned short* src_sorted = (unsigned short*)p;
    p += (size_t)(N_NODES * CAPN + 128) * 2;  // fixed regions + prefetch pad

    encode_prep_kernel<<<ENC_BLOCKS + PREP_BLOCKS, 256, 0, stream>>>(
        feats0, feats1, enc_w0, enc_b0, enc_w1, enc_b1, node_row_idx, xh, xf8,
        cnt,
        w_self0, w_neigh0, w_self1, w_neigh1, head_w, BT0, BT1, hwbh, hwbl);

    scatter_kernel<<<NSCAT, 256, 0, stream>>>(e_src, e_dst, cnt, src_sorted);

    // Layer 0
    aggregate_kernel<<<(N_NODES / 2 * 64 + 255) / 256, 256, 0, stream>>>(
        xf8, cnt, src_sorted, ah);
    gemm_mfma<<<(N_NODES + BM - 1) / BM, 512, 0, stream>>>(
        xh, ah, xf8, BT0, b0, 1, hwbh, hwbl, head_b, (float*)d_out);

    // Layer 1 (fused head)
    aggregate_kernel<<<(N_NODES / 2 * 64 + 255) / 256, 256, 0, stream>>>(
        xf8, cnt, src_sorted, ah);
    gemm_mfma<<<(N_NODES + BM - 1) / BM, 512, 0, stream>>>(
        xh, ah, xf8, BT1, b1, 2, hwbh, hwbl, head_b, (float*)d_out);
}

// Round 10
// 197.384 us; speedup vs baseline: 1.1369x; 1.1369x over previous
//
#include <hip/hip_runtime.h>
#include <hip/hip_bf16.h>

#define N_NODES 50000
#define N_EDGES 800000
#define C 128
#define D_IN 32
#define T0 25000
#define OUT_DIM 16
#define NBUCKETS ((N_NODES + 255) / 256)      // 196, bucket = dst>>8
#define CAP 4608                              // bucket region capacity (8-mult)
#define NB1 512
#define CHUNK1 ((N_EDGES + NB1 - 1) / NB1)    // 1563
#define ENC_BLOCKS 512
#define PREP_ITEMS (2 * 128 * 256 + 2 * 16 * 128)
#define PREP_BLOCKS ((PREP_ITEMS + 255) / 256)

// Pipeline (7 dispatches): mega{enc+prep+cursor-zero} -> bucket1 -> bucket2
// -> [agg -> gemm] x2.  No scan kernel: pairs/src_sorted live in FIXED
// per-bucket regions of CAP entries; per-node (beg,cnt) in nodeinfo[].
// R9 lesson: do NOT replace the two-phase binning with a single-pass
// scatter — random 2-byte stores across 6.4 MB caused ~28x write
// amplification (44 MB WRITE_SIZE, 60 us). Bucket-local scatter is the
// point of this structure.
// Feature storage: bf16 plane xh[N][128] (GEMM self operand) + fp8 e4m3
// plane xf8[N][128] (gather operand ONLY; one 128-B line per row).
// GEMM K=256: segs {xh*Ws_hi, ah*Wn_hi}. Layer-1 fuses the head.
// Aggregate: TWO nodes per wave; 16 contiguous edge-slots per node per
// iteration; 1 uint4 index load (next-iter prefetched) + 8 uint2 fp8 row
// gathers in flight; out-of-range slots use CONSTANT row 0 (L1/L2-hot,
// no dependent clamp-index load) and are predicated out.

typedef __attribute__((ext_vector_type(8))) short short8;
typedef __attribute__((ext_vector_type(4))) float f32x4;
typedef __attribute__((ext_vector_type(2))) float f32x2;

__device__ __forceinline__ unsigned short f2bf(float f) {
    union { float f; unsigned int i; } u; u.f = f;
    unsigned int x = u.i;
    unsigned int r = x + 0x7fffu + ((x >> 16) & 1u);
    return (unsigned short)(r >> 16);
}
__device__ __forceinline__ float bf2f(unsigned short h) {
    union { unsigned int i; float f; } u; u.i = ((unsigned int)h) << 16;
    return u.f;
}
__device__ __forceinline__ float lo_f(unsigned int w) {
    union { unsigned int i; float f; } u; u.i = w << 16;
    return u.f;
}
__device__ __forceinline__ float hi_f(unsigned int w) {
    union { unsigned int i; float f; } u; u.i = w & 0xffff0000u;
    return u.f;
}
__device__ __forceinline__ void async16(void* lds, const void* g) {
    __builtin_amdgcn_global_load_lds(
        (const __attribute__((address_space(1))) void*)g,
        (__attribute__((address_space(3))) void*)lds, 16, 0, 0);
}
// decode 8 fp8 (e4m3) bytes -> accumulate into a[0..7]
__device__ __forceinline__ void add8f8(float* a, uint2 v) {
    f32x2 p;
    p = __builtin_amdgcn_cvt_pk_f32_fp8(v.x, false); a[0] += p.x; a[1] += p.y;
    p = __builtin_amdgcn_cvt_pk_f32_fp8(v.x, true);  a[2] += p.x; a[3] += p.y;
    p = __builtin_amdgcn_cvt_pk_f32_fp8(v.y, false); a[4] += p.x; a[5] += p.y;
    p = __builtin_amdgcn_cvt_pk_f32_fp8(v.y, true);  a[6] += p.x; a[7] += p.y;
}
// pack 8 floats -> 8 fp8 (e4m3) bytes, RNE+saturate
__device__ __forceinline__ uint2 pack8f8(const float* a) {
    int w0 = 0, w1 = 0;
    w0 = __builtin_amdgcn_cvt_pk_fp8_f32(a[0], a[1], w0, false);
    w0 = __builtin_amdgcn_cvt_pk_fp8_f32(a[2], a[3], w0, true);
    w1 = __builtin_amdgcn_cvt_pk_fp8_f32(a[4], a[5], w1, false);
    w1 = __builtin_amdgcn_cvt_pk_fp8_f32(a[6], a[7], w1, true);
    return make_uint2((unsigned)w0, (unsigned)w1);
}

// ---------------------------------------------------------------------------
// Mega-kernel: encode (blocks 0..511, row_idx software-pipelined) +
// weight prep (512..; first prep block also zeroes bucket_cursor).
// ---------------------------------------------------------------------------
__global__ __launch_bounds__(256) void encode_prep_kernel(
    const float* __restrict__ feats0, const float* __restrict__ feats1,
    const float* __restrict__ w0, const float* __restrict__ b0,
    const float* __restrict__ w1, const float* __restrict__ b1,
    const int* __restrict__ row_idx, unsigned short* __restrict__ xh,
    unsigned char* __restrict__ xf8,
    int* __restrict__ bucket_cursor,
    const float* __restrict__ ws0, const float* __restrict__ wn0,
    const float* __restrict__ ws1, const float* __restrict__ wn1,
    const float* __restrict__ hw,
    unsigned short* __restrict__ BT0, unsigned short* __restrict__ BT1,
    unsigned short* __restrict__ hwbh, unsigned short* __restrict__ hwbl)
{
    if (blockIdx.x >= ENC_BLOCKS) {
        // ---- cursor zero (first prep block) ----
        if (blockIdx.x == ENC_BLOCKS && threadIdx.x < NBUCKETS)
            bucket_cursor[threadIdx.x] = 0;
        // ---- weight prep ----
        int idx = (blockIdx.x - ENC_BLOCKS) * 256 + threadIdx.x;
        const int per_layer = 128 * 256;
        if (idx < 2 * per_layer) {
            int lyr = idx / per_layer;
            int rem = idx - lyr * per_layer;
            int n = rem >> 8;
            int k = rem & 255;
            int seg = k >> 7;     // 0:Ws_hi 1:Wn_hi
            int ch = k & 127;
            const float* W = (lyr == 0) ? (seg ? wn0 : ws0)
                                        : (seg ? wn1 : ws1);
            (lyr == 0 ? BT0 : BT1)[(size_t)n * 256 + k] =
                f2bf(W[ch * 128 + n]);
            return;
        }
        int jdx = idx - 2 * per_layer;
        if (jdx >= 2 * 16 * 128) return;
        int plane = jdx >> 11;
        int rem = jdx & 2047;
        int n = rem >> 7;
        int k = rem & 127;
        float v = hw[k * OUT_DIM + n];
        unsigned short hi = f2bf(v);
        (plane ? hwbl : hwbh)[n * 136 + k] = plane ? f2bf(v - bf2f(hi)) : hi;
        return;
    }

    // ---- encode (pipelined row_idx prefetch) ----
    __shared__ float sw0[D_IN * C];
    __shared__ float sw1[D_IN * C];
    __shared__ float sb0[C];
    __shared__ float sb1[C];
    for (int i = threadIdx.x; i < D_IN * C; i += blockDim.x) {
        sw0[i] = w0[i];
        sw1[i] = w1[i];
    }
    if (threadIdx.x < C) {
        sb0[threadIdx.x] = b0[threadIdx.x];
        sb1[threadIdx.x] = b1[threadIdx.x];
    }
    __syncthreads();

    const int STEP = ENC_BLOCKS * 16;
    int j = threadIdx.x & 15;
    int ln = threadIdx.x >> 4;
    int n = blockIdx.x * 16 + ln;
    int r = (n < N_NODES) ? row_idx[n] : 0;
    for (; n < N_NODES; n += STEP) {
        int nn = n + STEP;
        int rn = (nn < N_NODES) ? row_idx[nn] : 0;
        const float* f = (r < T0) ? (feats0 + (size_t)r * D_IN)
                                  : (feats1 + (size_t)(r - T0) * D_IN);
        const float* W = (r < T0) ? sw0 : sw1;
        const float* B = (r < T0) ? sb0 : sb1;
        float4 f4[8];
#pragma unroll
        for (int i = 0; i < 8; ++i) f4[i] = ((const float4*)f)[i];
        float acc[8];
#pragma unroll
        for (int cc = 0; cc < 8; ++cc) acc[cc] = B[8 * j + cc];
#pragma unroll
        for (int k = 0; k < D_IN; ++k) {
            float fk = ((const float*)f4)[k];
            float4 wa = *(const float4*)&W[k * C + 8 * j];
            float4 wb = *(const float4*)&W[k * C + 8 * j + 4];
            acc[0] += fk * wa.x; acc[1] += fk * wa.y;
            acc[2] += fk * wa.z; acc[3] += fk * wa.w;
            acc[4] += fk * wb.x; acc[5] += fk * wb.y;
            acc[6] += fk * wb.z; acc[7] += fk * wb.w;
        }
        short8 h8;
#pragma unroll
        for (int cc = 0; cc < 8; ++cc) h8[cc] = (short)f2bf(acc[cc]);
        *(short8*)(xh + (size_t)n * 128 + 8 * j) = h8;
        *(uint2*)(xf8 + (size_t)n * 128 + 8 * j) = pack8f8(acc);
        r = rn;
    }
}

// ---------------------------------------------------------------------------
// bucket1: chunk histogram + region-cursor reserve + scatter into fixed
// per-bucket regions pairs[b*CAP ...].
// ---------------------------------------------------------------------------
__global__ __launch_bounds__(256) void bucket1_kernel(
    const int* __restrict__ src, const int* __restrict__ dst,
    int* __restrict__ bucket_cursor, unsigned int* __restrict__ pairs)
{
    __shared__ int hist[NBUCKETS];
    __shared__ int base[NBUCKETS];
    __shared__ int cur[NBUCKETS];
    int tid = threadIdx.x;
    for (int i = tid; i < NBUCKETS; i += 256) { hist[i] = 0; cur[i] = 0; }
    __syncthreads();
    int ebeg = blockIdx.x * CHUNK1;
    int eend = ebeg + CHUNK1;
    if (eend > N_EDGES) eend = N_EDGES;
    for (int e = ebeg + tid; e < eend; e += 256)
        atomicAdd(&hist[dst[e] >> 8], 1);
    __syncthreads();
    for (int i = tid; i < NBUCKETS; i += 256)
        if (hist[i] > 0) base[i] = atomicAdd(&bucket_cursor[i], hist[i]);
    __syncthreads();
    for (int e = ebeg + tid; e < eend; e += 256) {
        int d = dst[e];
        int b = d >> 8;
        int pos = b * CAP + base[b] + atomicAdd(&cur[b], 1);
        pairs[pos] = ((unsigned)(d & 255) << 16) | (unsigned)src[e];
    }
}

// ---------------------------------------------------------------------------
// bucket2: per-bucket local CSR -> nodeinfo (beg,cnt), inv_deg, src_sorted
// scattered within the bucket's fixed region.
// ---------------------------------------------------------------------------
__global__ __launch_bounds__(256) void bucket2_kernel(
    const unsigned int* __restrict__ pairs, const int* __restrict__ bucket_cursor,
    uint2* __restrict__ nodeinfo, float* __restrict__ inv_deg,
    unsigned short* __restrict__ src_sorted)
{
    __shared__ int cnt[256];
    __shared__ int noff[256];
    __shared__ int cur[256];
    __shared__ int ws[4];
    int b = blockIdx.x;
    int n0 = b << 8;
    int tid = threadIdx.x;
    int bb = b * CAP;
    int be = bb + bucket_cursor[b];
    cnt[tid] = 0;
    cur[tid] = 0;
    __syncthreads();
    for (int e = bb + tid; e < be; e += 256)
        atomicAdd(&cnt[pairs[e] >> 16], 1);
    __syncthreads();
    int c = cnt[tid];
    int lane = tid & 63, wid = tid >> 6;
    int v = c;
#pragma unroll
    for (int off = 1; off < 64; off <<= 1) {
        int s = __shfl_up(v, off, 64);
        if (lane >= off) v += s;
    }
    if (lane == 63) ws[wid] = v;
    __syncthreads();
    if (tid == 0) {
        int run = 0;
#pragma unroll
        for (int jj = 0; jj < 4; ++jj) { int s = ws[jj]; ws[jj] = run; run += s; }
    }
    __syncthreads();
    int o = bb + ws[wid] + (v - c);
    noff[tid] = o;
    int n = n0 + tid;
    if (n < N_NODES) {
        nodeinfo[n] = make_uint2((unsigned)o, (unsigned)c);
        inv_deg[n] = 1.0f / (float)(c > 0 ? c : 1);
    }
    __syncthreads();
    for (int e = bb + tid; e < be; e += 256) {
        unsigned int p = pairs[e];
        int local = p >> 16;
        int pos = noff[local] + atomicAdd(&cur[local], 1);
        src_sorted[pos] = (unsigned short)(p & 0xffffu);
    }
}

// ---------------------------------------------------------------------------
// Aggregate: TWO nodes per wave. lane = p*32 + h*16 + u; p selects node,
// h the 8-slot half of the node's 16-slot window, u the channel group.
// Gathers fp8 rows (128 B = ONE cache line each): 1 uint4 index load
// (next-iter prefetched) + 8 uint2 row gathers in flight per iteration.
// Out-of-range slots use constant row 0 (always-cached, no dependent
// clamp-index load) and are predicated out of the accumulate.
// ---------------------------------------------------------------------------
__global__ __launch_bounds__(256, 8) void aggregate_kernel(
    const unsigned char* __restrict__ xf8, const uint2* __restrict__ nodeinfo,
    const unsigned short* __restrict__ src_sorted,
    const float* __restrict__ inv_deg, unsigned short* __restrict__ ah)
{
    int wpair = (blockIdx.x * blockDim.x + threadIdx.x) >> 6;
    int lane = threadIdx.x & 63;
    if (wpair >= N_NODES / 2) return;
    int p = lane >> 5;
    int h = (lane >> 4) & 1;
    int u = lane & 15;
    int node = wpair * 2 + p;
    uint2 ni = nodeinfo[node];
    float inv = inv_deg[node];          // issue alongside nodeinfo chain
    int beg = (int)ni.x;
    int end = beg + (int)ni.y;
    const unsigned char* xu = xf8 + u * 8;
    float acc[8];
#pragma unroll
    for (int j = 0; j < 8; ++j) acc[j] = 0.f;

    int e0 = beg & ~7;
    if (e0 < end) {
        uint4 sv = *(const uint4*)(src_sorted + e0 + h * 8);
        for (int e = e0; e < end; e += 16) {
            // prefetch next window's indices (overflow lands in the next
            // bucket's allocated region; values unused on last iteration)
            uint4 svn = *(const uint4*)(src_sorted + e + 16 + h * 8);
            int b8 = e + h * 8;
            uint2 v[8];
#pragma unroll
            for (int t = 0; t < 8; ++t) {
                unsigned int w2 = ((const unsigned int*)&sv)[t >> 1];
                int row = (t & 1) ? (int)(w2 >> 16) : (int)(w2 & 0xffffu);
                int idx = b8 + t;
                if (idx < beg || idx >= end) row = 0;
                v[t] = *(const uint2*)(xu + (size_t)row * 128);
            }
#pragma unroll
            for (int t = 0; t < 8; ++t) {
                int idx = b8 + t;
                if (idx >= beg && idx < end) add8f8(acc, v[t]);
            }
            sv = svn;
        }
    }

    // reduce across the two 8-slot halves (h dimension) within each node
#pragma unroll
    for (int j = 0; j < 8; ++j)
        acc[j] += __shfl_xor(acc[j], 16);
    if ((lane & 16) == 0) {
        short8 hv;
#pragma unroll
        for (int j = 0; j < 8; ++j)
            hv[j] = (short)f2bf(acc[j] * inv);
        *(short8*)(ah + (size_t)node * 128 + u * 8) = hv;
    }
}

// ---------------------------------------------------------------------------
// Layer GEMM: 512 thr / 8 waves, tile 128x128, K=256 in 2 chunks of 128:
// {xh*Ws_hi, ah*Wn_hi}. BT row = 256 slots (512 B).
// mode=1: relu, write xh (bf16) + xf8 (fp8) planes. mode=2: fused head.
// ---------------------------------------------------------------------------
#define BM 128
__global__ __launch_bounds__(512) void gemm_mfma(
    unsigned short* __restrict__ xh, const unsigned short* __restrict__ ah,
    unsigned char* __restrict__ xf8,
    const unsigned short* __restrict__ BT, const float* __restrict__ bias,
    int mode,
    const unsigned short* __restrict__ hwbh,
    const unsigned short* __restrict__ hwbl,
    const float* __restrict__ hb, float* __restrict__ out)
{
    __shared__ uint4 smem4[4096];           // 64 KB: As 32K | Bs 32K / th
    char* As = (char*)smem4;
    char* Bs = (char*)smem4 + 32768;
    __shared__ float bias_s[C];
    __shared__ unsigned short hwh_s[16 * 136];
    __shared__ unsigned short hwl_s[16 * 136];
    __shared__ float hb_s[OUT_DIM];

    int tid = threadIdx.x;
    int w = tid >> 6, l = tid & 63;
    int row0 = blockIdx.x * BM;
    if (tid < C) bias_s[tid] = bias[tid];
    if (mode == 2) {
        for (int i = tid; i < 16 * 136; i += 512) {
            hwh_s[i] = hwbh[i];
            hwl_s[i] = hwbl[i];
        }
        if (tid < OUT_DIM) hb_s[tid] = hb[tid];
    }

    f32x4 acc[2][4];
#pragma unroll
    for (int mt = 0; mt < 2; ++mt)
#pragma unroll
        for (int nt = 0; nt < 4; ++nt)
            acc[mt][nt] = (f32x4)(0.f);

    int wm = w & 3;
    int wn = w >> 2;
    int quad = l >> 4;
    int mrow = l & 15;

    for (int c = 0; c < 2; ++c) {
        const char* abase = (const char*)(c == 0 ? xh : ah);
#pragma unroll
        for (int i = 0; i < 4; ++i) {
            int off = i * 8192 + tid * 16;
            int rl = off >> 8;
            int row = row0 + rl;
            if (row > N_NODES - 1) row = N_NODES - 1;
            int u = ((off >> 4) & 15) ^ (rl & 15);
            async16(As + off, abase + (size_t)row * 256 + u * 16);
        }
#pragma unroll
        for (int i = 0; i < 4; ++i) {
            int off = i * 8192 + tid * 16;
            int n = off >> 8;
            int u = ((off >> 4) & 15) ^ (n & 15);
            async16(Bs + off, (const char*)BT + (size_t)n * 512 + c * 256 + u * 16);
        }
        __syncthreads();
#pragma unroll
        for (int ks = 0; ks < 4; ++ks) {
            int cu = ks * 4 + quad;
            int swz = (cu ^ mrow) * 16;
            short8 a0 = *(const short8*)(As + (wm * 32 + mrow) * 256 + swz);
            short8 a1 = *(const short8*)(As + (wm * 32 + 16 + mrow) * 256 + swz);
            short8 b[4];
#pragma unroll
            for (int nt = 0; nt < 4; ++nt)
                b[nt] = *(const short8*)(Bs + (wn * 64 + nt * 16 + mrow) * 256 + swz);
#pragma unroll
            for (int nt = 0; nt < 4; ++nt) {
                acc[0][nt] = __builtin_amdgcn_mfma_f32_16x16x32_bf16(a0, b[nt], acc[0][nt], 0, 0, 0);
                acc[1][nt] = __builtin_amdgcn_mfma_f32_16x16x32_bf16(a1, b[nt], acc[1][nt], 0, 0, 0);
            }
        }
        __syncthreads();
    }

    // epilogue: bf16 tile in LDS, XOR-swizzled (unit' = unit ^ (rl&15))
    char* th = (char*)smem4;            // 32 KB: 128 rows x 256 B
    int relu = (mode == 1);
#pragma unroll
    for (int mt = 0; mt < 2; ++mt)
#pragma unroll
        for (int nt = 0; nt < 4; ++nt) {
            int col = wn * 64 + nt * 16 + mrow;
#pragma unroll
            for (int r = 0; r < 4; ++r) {
                int rl = wm * 32 + mt * 16 + quad * 4 + r;
                float v = acc[mt][nt][r] + bias_s[col];
                if (relu) v = fmaxf(v, 0.f);
                int su = (col >> 3) ^ (rl & 15);
                *(unsigned short*)(th + rl * 256 + su * 16 + (col & 7) * 2) =
                    f2bf(v);
            }
        }
    __syncthreads();

    if (mode == 1) {
        // unswizzling copy-out to xh (bf16) + xf8 (fp8)
#pragma unroll
        for (int i = 0; i < 4; ++i) {
            int off = i * 8192 + tid * 16;
            int rl = off >> 8;
            int su = (((off >> 4) & 15) ^ (rl & 15)) * 16;
            int row = row0 + rl;
            if (row < N_NODES) {
                uint4 tv = *(const uint4*)(th + rl * 256 + su);
                *(uint4*)((char*)xh + (size_t)row * 256 + (off & 255)) = tv;
                float fv[8];
                fv[0] = lo_f(tv.x); fv[1] = hi_f(tv.x);
                fv[2] = lo_f(tv.y); fv[3] = hi_f(tv.y);
                fv[4] = lo_f(tv.z); fv[5] = hi_f(tv.z);
                fv[6] = lo_f(tv.w); fv[7] = hi_f(tv.w);
                *(uint2*)(xf8 + (size_t)row * 128 + ((off & 255) >> 1)) =
                    pack8f8(fv);
            }
        }
    } else {
        // fused head: out_tile = th @ (hwh + hwl) + hb
        f32x4 hacc = (f32x4)(0.f);
        const unsigned short* Bp[2] = {hwh_s, hwl_s};
#pragma unroll
        for (int ps = 0; ps < 2; ++ps) {
#pragma unroll
            for (int ks = 0; ks < 4; ++ks) {
                int su = ((ks * 4 + quad) ^ mrow) * 16;
                short8 a = *(const short8*)(th + (w * 16 + mrow) * 256 + su);
                short8 b = *(const short8*)((const char*)Bp[ps] +
                                            mrow * 272 + ks * 64 + quad * 16);
                hacc = __builtin_amdgcn_mfma_f32_16x16x32_bf16(a, b, hacc, 0, 0, 0);
            }
        }
        float bb = hb_s[mrow];
#pragma unroll
        for (int r = 0; r < 4; ++r) {
            int grow = row0 + w * 16 + quad * 4 + r;
            if (grow < N_NODES)
                out[(size_t)grow * OUT_DIM + mrow] = hacc[r] + bb;
        }
    }
}

// ---------------------------------------------------------------------------
extern "C" void kernel_launch(void* const* d_in, const int* in_sizes, int n_in,
                              void* d_out, int out_size, void* d_ws, size_t ws_size,
                              hipStream_t stream)
{
    const float* feats0 = (const float*)d_in[0];
    const float* feats1 = (const float*)d_in[1];
    const float* enc_w0 = (const float*)d_in[2];
    const float* enc_b0 = (const float*)d_in[3];
    const float* enc_w1 = (const float*)d_in[4];
    const float* enc_b1 = (const float*)d_in[5];
    const float* w_self0 = (const float*)d_in[6];
    const float* w_neigh0 = (const float*)d_in[7];
    const float* b0 = (const float*)d_in[8];
    const float* w_self1 = (const float*)d_in[9];
    const float* w_neigh1 = (const float*)d_in[10];
    const float* b1 = (const float*)d_in[11];
    const float* head_w = (const float*)d_in[12];
    const float* head_b = (const float*)d_in[13];
    const int* node_row_idx = (const int*)d_in[14];
    const int* edge_index = (const int*)d_in[15];
    const int* e_src = edge_index;
    const int* e_dst = edge_index + N_EDGES;

    char* p = (char*)d_ws;
    unsigned short* xh = (unsigned short*)p;  p += (size_t)N_NODES * C * 2;
    unsigned short* ah = (unsigned short*)p;  p += (size_t)N_NODES * C * 2;
    unsigned char* xf8 = (unsigned char*)p;   p += (size_t)N_NODES * C;
    unsigned short* BT0 = (unsigned short*)p; p += (size_t)128 * 256 * 2;
    unsigned short* BT1 = (unsigned short*)p; p += (size_t)128 * 256 * 2;
    unsigned short* hwbh = (unsigned short*)p; p += (size_t)16 * 136 * 2;
    unsigned short* hwbl = (unsigned short*)p; p += (size_t)16 * 136 * 2;
    float* inv_deg = (float*)p;    p += (size_t)N_NODES * 4;
    uint2* nodeinfo = (uint2*)p;   p += (size_t)N_NODES * 8;
    int* bucket_cursor = (int*)p;  p += (size_t)(NBUCKETS + 8) * 4;
    unsigned short* src_sorted = (unsigned short*)p;
    p += (size_t)(NBUCKETS * CAP + 32) * 2;   // fixed regions + uint4 pad
    // pairs aliases ah (ah unwritten until aggregate, which runs after
    // bucket2 on the same stream): 196*4608*4 B = 3.6 MB <= 12.8 MB
    unsigned int* pairs = (unsigned int*)ah;

    encode_prep_kernel<<<ENC_BLOCKS + PREP_BLOCKS, 256, 0, stream>>>(
        feats0, feats1, enc_w0, enc_b0, enc_w1, enc_b1, node_row_idx, xh, xf8,
        bucket_cursor,
        w_self0, w_neigh0, w_self1, w_neigh1, head_w, BT0, BT1, hwbh, hwbl);

    bucket1_kernel<<<NB1, 256, 0, stream>>>(e_src, e_dst, bucket_cursor, pairs);
    bucket2_kernel<<<NBUCKETS, 256, 0, stream>>>(pairs, bucket_cursor,
                                                 nodeinfo, inv_deg, src_sorted);

    // Layer 0
    aggregate_kernel<<<(N_NODES / 2 * 64 + 255) / 256, 256, 0, stream>>>(
        xf8, nodeinfo, src_sorted, inv_deg, ah);
    gemm_mfma<<<(N_NODES + BM - 1) / BM, 512, 0, stream>>>(
        xh, ah, xf8, BT0, b0, 1, hwbh, hwbl, head_b, (float*)d_out);

    // Layer 1 (fused head)
    aggregate_kernel<<<(N_NODES / 2 * 64 + 255) / 256, 256, 0, stream>>>(
        xf8, nodeinfo, src_sorted, inv_deg, ah);
    gemm_mfma<<<(N_NODES + BM - 1) / BM, 512, 0, stream>>>(
        xh, ah, xf8, BT1, b1, 2, hwbh, hwbl, head_b, (float*)d_out);
}